// Round 2
// baseline (355.930 us; speedup 1.0000x reference)
//
#include <hip/hip_runtime.h>

// B=8, N=4096, Din=128, Dout=256.
// bf16 2-way split (hi/mid) + 3 product-class MFMAs = ~24-bit GEMMs (validated:
// absmax 0.5 vs threshold 2.42; bf16-only fails at 22.4).
// R7: two-kernel split. R6 showed occupancy 43->60% with ZERO dur change ->
// latency/serialization-bound, not resource-bound. Root causes attacked:
//  (a) phase A had 36 scalar global loads/thread in a 4-deep serial chain and
//      24 scalar ds_write_u16 -> now a standalone streaming kernel: 4 channels
//      per thread => 9 aligned float4 loads + 6 short4 stores to GLOBAL aT
//      (bf16 hi/mid planes, same numerics as the old LDS path).
//  (b) GEMM kernel reads A-fragments of GEMM1 directly from global (24KB/block
//      tile, L1-resident after first touch) -> no aT LDS traffic, and the
//      kernel has exactly ONE barrier (around the Yt transpose stash).
//  (c) epilogue uses live acc1 again (removes 48 ds_read_u16/wave + conflicts);
//      __launch_bounds__(512,4) gives 128 regs for pipelining the unrolled
//      K-loops (occupancy proven irrelevant in R6).
#define TT 16
#define NBLK 2048
#define LDY 264   // Yt row stride (bf16): 256 + 8 pad, 16B-aligned rows

typedef short s16x8 __attribute__((ext_vector_type(8)));
typedef float f32x4 __attribute__((ext_vector_type(4)));

__device__ __forceinline__ unsigned short f2bf(float f) {
  union { float f; unsigned u; } v; v.f = f;
  unsigned r = v.u + 0x7FFFu + ((v.u >> 16) & 1u);   // RNE; inputs finite
  return (unsigned short)(r >> 16);
}
__device__ __forceinline__ float bf2f(unsigned short h) {
  union { unsigned u; float f; } v; v.u = ((unsigned)h) << 16;
  return v.f;
}
__device__ __forceinline__ void split2(float x, unsigned short& h, unsigned short& m) {
  h = f2bf(x);
  m = f2bf(x - bf2f(h));   // exact subtraction
}

__global__ __launch_bounds__(256) void prep_kernel(
    const float* __restrict__ A, const float* __restrict__ Bm,
    const float* __restrict__ C, const float* __restrict__ W,
    unsigned short* __restrict__ M3h, unsigned short* __restrict__ M3m,
    unsigned short* __restrict__ Wh, unsigned short* __restrict__ Wm) {
  int tid = blockIdx.x * 256 + threadIdx.x;
  if (tid < 128 * 256) {
    unsigned short h, m;
    split2(A[tid] + Bm[tid] + C[tid], h, m);
    M3h[tid] = h; M3m[tid] = m;
  } else {
    int t2 = tid - 128 * 256;
    unsigned short h, m;
    split2(W[t2], h, m);
    Wh[t2] = h; Wm[t2] = m;
  }
}

// ---- Phase A standalone: Gram-Schmidt + a = R^T X -> global bf16x2 aT ------
// aT layout (u16): [token(32768)][i(3)][dch(128)]; planes aTh / aTm.
// Thread handles 4 consecutive dch of one token: fully vectorized IO.
__global__ __launch_bounds__(256) void phaseA_kernel(
    const float* __restrict__ X, const float* __restrict__ J,
    unsigned short* __restrict__ aTh, unsigned short* __restrict__ aTm) {
  int tid = blockIdx.x * 256 + threadIdx.x;   // 0 .. 1048575
  int token = tid >> 5;                        // 32 threads per token
  int dch0 = (tid & 31) * 4;
  const float* Xp = X + ((long)token * 128 + dch0) * 3;   // 48B, 16B-aligned
  const float* Jp = J + ((long)token * 128 + dch0) * 6;   // 96B, 16B-aligned
  float xf[12], jf[24];
  #pragma unroll
  for (int q = 0; q < 3; ++q) *(float4*)(xf + 4 * q) = ((const float4*)Xp)[q];
  #pragma unroll
  for (int q = 0; q < 6; ++q) *(float4*)(jf + 4 * q) = ((const float4*)Jp)[q];

  unsigned short hs[3][4], ms[3][4];
  #pragma unroll
  for (int e = 0; e < 4; ++e) {
    float x0 = xf[3 * e], x1 = xf[3 * e + 1], x2 = xf[3 * e + 2];
    float j0 = jf[6 * e],     j1 = jf[6 * e + 1], j2 = jf[6 * e + 2];
    float j3 = jf[6 * e + 3], j4 = jf[6 * e + 4], j5 = jf[6 * e + 5];
    float c00 = j0, c01 = j2, c02 = j4;          // col0 of the 3x2
    float a20 = j1, a21 = j3, a22 = j5;          // col1
    float n1 = sqrtf(c00 * c00 + c01 * c01 + c02 * c02);
    float inv1 = 1.0f / fmaxf(n1, 1e-12f);
    float b10 = c00 * inv1, b11 = c01 * inv1, b12 = c02 * inv1;
    float pr = b10 * a20 + b11 * a21 + b12 * a22;
    float u0 = a20 - pr * b10, u1 = a21 - pr * b11, u2 = a22 - pr * b12;
    float n2 = sqrtf(u0 * u0 + u1 * u1 + u2 * u2);
    float inv2 = 1.0f / fmaxf(n2, 1e-12f);
    float b20 = u0 * inv2, b21 = u1 * inv2, b22 = u2 * inv2;
    float b30 = b11 * b22 - b12 * b21;
    float b31 = b12 * b20 - b10 * b22;
    float b32 = b10 * b21 - b11 * b20;
    split2(b10 * x0 + b11 * x1 + b12 * x2, hs[0][e], ms[0][e]);
    split2(b20 * x0 + b21 * x1 + b22 * x2, hs[1][e], ms[1][e]);
    split2(b30 * x0 + b31 * x1 + b32 * x2, hs[2][e], ms[2][e]);
  }
  long rb = (long)token * 384 + dch0;
  #pragma unroll
  for (int i = 0; i < 3; ++i) {
    short4 vh, vm;
    vh.x = hs[i][0]; vh.y = hs[i][1]; vh.z = hs[i][2]; vh.w = hs[i][3];
    vm.x = ms[i][0]; vm.y = ms[i][1]; vm.z = ms[i][2]; vm.w = ms[i][3];
    *(short4*)(aTh + rb + i * 128) = vh;   // 8B-aligned
    *(short4*)(aTm + rb + i * 128) = vm;
  }
}

// ---- GEMM1 + transpose stash + GEMM2 + VN-LeakyReLU ------------------------
__global__ __launch_bounds__(512, 4) void gemm_vnrelu(
    const unsigned short* __restrict__ aTh, const unsigned short* __restrict__ aTm,
    const unsigned short* __restrict__ M3h, const unsigned short* __restrict__ M3m,
    const unsigned short* __restrict__ Wh, const unsigned short* __restrict__ Wm,
    float* __restrict__ out) {
  __shared__ unsigned short smem[2 * 48 * LDY];   // Yt hi/mid planes, 50688 B

  const int tid = threadIdx.x;
  const int lane = tid & 63;
  const int w = tid >> 6;          // wave 0..7 -> f slice [32w, 32w+32)
  const int quad = lane >> 4;
  const int nl = lane & 15;
  const long g0 = (long)blockIdx.x * TT;
  const int b = (int)(g0 >> 12);   // N = 4096
  const int n0 = (int)(g0 & 4095);
  const int f0 = w * 32;
  const f32x4 zz = {0.f, 0.f, 0.f, 0.f};

  // ---------------- GEMM1: Y[j][f] = sum_e aT[j][e] * M3[f][e] (split x3) ----
  // A-fragments straight from global aT (L1/L2-resident tile, 48KB/block).
  f32x4 acc1[3][2];
  #pragma unroll
  for (int mt = 0; mt < 3; ++mt)
    #pragma unroll
    for (int nt = 0; nt < 2; ++nt) acc1[mt][nt] = zz;

  const unsigned short* aThb = aTh + (g0 + nl) * 384;   // token g0+nl, i=mt
  const unsigned short* aTmb = aTm + (g0 + nl) * 384;

  #pragma unroll
  for (int ks = 0; ks < 4; ++ks) {
    int e0 = ks * 32 + quad * 8;
    s16x8 bh[2], bm[2];
    #pragma unroll
    for (int nt = 0; nt < 2; ++nt) {
      int bo = (f0 + nt * 16 + nl) * 128 + e0;
      bh[nt] = *(const s16x8*)(M3h + bo);
      bm[nt] = *(const s16x8*)(M3m + bo);
    }
    #pragma unroll
    for (int mt = 0; mt < 3; ++mt) {
      s16x8 ah = *(const s16x8*)(aThb + mt * 128 + e0);
      s16x8 am = *(const s16x8*)(aTmb + mt * 128 + e0);
      #pragma unroll
      for (int nt = 0; nt < 2; ++nt) {
        f32x4 a = acc1[mt][nt];
        a = __builtin_amdgcn_mfma_f32_16x16x32_bf16(ah, bh[nt], a, 0, 0, 0);
        a = __builtin_amdgcn_mfma_f32_16x16x32_bf16(ah, bm[nt], a, 0, 0, 0);
        a = __builtin_amdgcn_mfma_f32_16x16x32_bf16(am, bh[nt], a, 0, 0, 0);
        acc1[mt][nt] = a;
      }
    }
  }

  // ---------------- stash Y as bf16x2 (exact split of fp32 acc) -------------
  // Only use of LDS; smem has no prior readers -> no barrier before writes.
  unsigned short* Yth = smem;
  unsigned short* Ytm = smem + 48 * LDY;
  #pragma unroll
  for (int mt = 0; mt < 3; ++mt)
    #pragma unroll
    for (int nt = 0; nt < 2; ++nt)
      #pragma unroll
      for (int r = 0; r < 4; ++r) {
        unsigned short h, m;
        split2(acc1[mt][nt][r], h, m);
        int yo = (mt * 16 + quad * 4 + r) * LDY + f0 + nt * 16 + nl;
        Yth[yo] = h; Ytm[yo] = m;
      }
  __syncthreads();   // the single barrier of the kernel

  // ---------------- GEMM2: d[j][o] = sum_c Yt[j][c] * W[o][c] (split x3) ----
  f32x4 acc2[3][2];
  #pragma unroll
  for (int mt = 0; mt < 3; ++mt)
    #pragma unroll
    for (int nt = 0; nt < 2; ++nt) acc2[mt][nt] = zz;

  #pragma unroll
  for (int ks = 0; ks < 8; ++ks) {
    int c0 = ks * 32 + quad * 8;
    s16x8 bh[2], bm[2];
    #pragma unroll
    for (int nt = 0; nt < 2; ++nt) {
      int bo = (f0 + nt * 16 + nl) * 256 + c0;
      bh[nt] = *(const s16x8*)(Wh + bo);
      bm[nt] = *(const s16x8*)(Wm + bo);
    }
    #pragma unroll
    for (int mt = 0; mt < 3; ++mt) {
      int ao = (mt * 16 + nl) * LDY + c0;
      s16x8 ah = *(const s16x8*)(Yth + ao);
      s16x8 am = *(const s16x8*)(Ytm + ao);
      #pragma unroll
      for (int nt = 0; nt < 2; ++nt) {
        f32x4 a = acc2[mt][nt];
        a = __builtin_amdgcn_mfma_f32_16x16x32_bf16(ah, bh[nt], a, 0, 0, 0);
        a = __builtin_amdgcn_mfma_f32_16x16x32_bf16(ah, bm[nt], a, 0, 0, 0);
        a = __builtin_amdgcn_mfma_f32_16x16x32_bf16(am, bh[nt], a, 0, 0, 0);
        acc2[mt][nt] = a;
      }
    }
  }

  // ---------------- VN-LeakyReLU (lane-local) + float4 stores ---------------
  // lane holds x_i = acc1[i][nt][r], d_i = acc2[i][nt][r] at the SAME (f, t):
  // f = f0 + nt*16 + nl, t = quad*4 + r.
  #pragma unroll
  for (int nt = 0; nt < 2; ++nt) {
    int f = f0 + nt * 16 + nl;
    float* ob = out + ((long)(b * 256 + f) * 3) * 4096 + n0 + quad * 4;
    float o[3][4];
    #pragma unroll
    for (int r = 0; r < 4; ++r) {
      float x0 = acc1[0][nt][r], x1 = acc1[1][nt][r], x2 = acc1[2][nt][r];
      float d0 = acc2[0][nt][r], d1 = acc2[1][nt][r], d2 = acc2[2][nt][r];
      float dot = x0 * d0 + x1 * d1 + x2 * d2;
      float dn = d0 * d0 + d1 * d1 + d2 * d2;
      float s = (dot < 0.0f) ? (0.8f * dot / (dn + 1e-6f)) : 0.0f;
      o[0][r] = x0 - s * d0;
      o[1][r] = x1 - s * d1;
      o[2][r] = x2 - s * d2;
    }
    #pragma unroll
    for (int i = 0; i < 3; ++i)
      *(float4*)(ob + ((long)i * 4096)) = make_float4(o[i][0], o[i][1], o[i][2], o[i][3]);
  }
}

extern "C" void kernel_launch(void* const* d_in, const int* in_sizes, int n_in,
                              void* d_out, int out_size, void* d_ws, size_t ws_size,
                              hipStream_t stream) {
  const float* X = (const float*)d_in[0];   // [8,4096,128,3]
  const float* J = (const float*)d_in[1];   // [8,4096,128,3,2]
  const float* A = (const float*)d_in[2];   // [256,128]
  const float* B = (const float*)d_in[3];   // [256,128]
  const float* C = (const float*)d_in[4];   // [256,128]
  const float* W = (const float*)d_in[5];   // [256,256]
  unsigned short* M3h = (unsigned short*)d_ws;        // 32768 u16
  unsigned short* M3m = M3h + 128 * 256;
  unsigned short* Wh  = M3m + 128 * 256;              // 65536 u16
  unsigned short* Wm  = Wh + 256 * 256;
  unsigned short* aTh = Wm + 256 * 256;               // 32768*384 u16 = 25.2MB
  unsigned short* aTm = aTh + (long)32768 * 384;      // total ws ~50.8MB
  float* out = (float*)d_out;               // [8,256,3,4096]

  phaseA_kernel<<<4096, 256, 0, stream>>>(X, J, aTh, aTm);
  prep_kernel<<<(128 * 256 + 256 * 256) / 256, 256, 0, stream>>>(
      A, B, C, W, M3h, M3m, Wh, Wm);
  gemm_vnrelu<<<NBLK, 512, 0, stream>>>(
      aTh, aTm, M3h, M3m, Wh, Wm, out);
}

// Round 5
// 287.838 us; speedup vs baseline: 1.2366x; 1.2366x over previous
//
#include <hip/hip_runtime.h>

// B=8, N=4096, Din=128, Dout=256. TT=16 tokens/block -> M = 3*16 = 48 rows.
// bf16 2-way split (hi/mid) + 3 product-class MFMAs = ~24-bit GEMMs (validated:
// absmax 0.5 vs threshold 2.42).
// R8 (2nd resubmit — R3/R4 benches both died in GPUAcquisitionTimeout; the
// kernel has never run): back to monolithic (R7 split cost +50us for -12us).
// R7's datum: GEMM phases alone are 151us vs 28us MFMA floor with all pipes
// <16% busy, and per-wave elapsed ~= (#loads x L2 latency) SERIALIZED.
// VGPR_Count=48 says the compiler had no registers to keep loads in flight.
// This round:
//  (a) explicit rolling prefetch of all B-operand tiles (static-indexed reg
//      arrays, 2-3 ks deep) so ~8-12 16B loads are in flight per wave;
//  (b) vectorized phase A (4ch/thread: 9 float4 loads, 6 short4 LDS writes);
//  (c) de-unioned LDS (aT 26KB + Yt 50KB = 76.8KB, 2 blocks/CU) -> 2 barriers;
//  (d) epilogue re-reads x from Yt stash (R6-validated) so acc1 dies early;
//      steady live set ~110-125 regs under __launch_bounds__(512,4) cap 128.
#define TT 16
#define NBLK 2048
#define LDA 136   // aT row stride (bf16): 128 + 8 pad
#define LDY 264   // Yt row stride (bf16): 256 + 8 pad

typedef short s16x8 __attribute__((ext_vector_type(8)));
typedef float f32x4 __attribute__((ext_vector_type(4)));

__device__ __forceinline__ unsigned short f2bf(float f) {
  union { float f; unsigned u; } v; v.f = f;
  unsigned r = v.u + 0x7FFFu + ((v.u >> 16) & 1u);   // RNE; inputs finite
  return (unsigned short)(r >> 16);
}
__device__ __forceinline__ float bf2f(unsigned short h) {
  union { unsigned u; float f; } v; v.u = ((unsigned)h) << 16;
  return v.f;
}
__device__ __forceinline__ void split2(float x, unsigned short& h, unsigned short& m) {
  h = f2bf(x);
  m = f2bf(x - bf2f(h));   // exact subtraction
}

__global__ __launch_bounds__(256) void prep_kernel(
    const float* __restrict__ A, const float* __restrict__ Bm,
    const float* __restrict__ C, const float* __restrict__ W,
    unsigned short* __restrict__ M3h, unsigned short* __restrict__ M3m,
    unsigned short* __restrict__ Wh, unsigned short* __restrict__ Wm) {
  int tid = blockIdx.x * 256 + threadIdx.x;
  if (tid < 128 * 256) {
    unsigned short h, m;
    split2(A[tid] + Bm[tid] + C[tid], h, m);
    M3h[tid] = h; M3m[tid] = m;
  } else {
    int t2 = tid - 128 * 256;
    unsigned short h, m;
    split2(W[t2], h, m);
    Wh[t2] = h; Wm[t2] = m;
  }
}

// rolling-prefetch load macros (all indices compile-time constant)
#define B1LOAD(ks) { \
  b1h[ks][0] = *(const s16x8*)(M3h + fB1 + (ks) * 32); \
  b1m[ks][0] = *(const s16x8*)(M3m + fB1 + (ks) * 32); \
  b1h[ks][1] = *(const s16x8*)(M3h + fB1 + 2048 + (ks) * 32); \
  b1m[ks][1] = *(const s16x8*)(M3m + fB1 + 2048 + (ks) * 32); }

#define W2LOAD(ks) { \
  w2h[ks][0] = *(const s16x8*)(Wh + fB2 + (ks) * 32); \
  w2m[ks][0] = *(const s16x8*)(Wm + fB2 + (ks) * 32); \
  w2h[ks][1] = *(const s16x8*)(Wh + fB2 + 4096 + (ks) * 32); \
  w2m[ks][1] = *(const s16x8*)(Wm + fB2 + 4096 + (ks) * 32); }

#define G1STEP(ks) { \
  const int e0 = (ks) * 32 + quad * 8; \
  _Pragma("unroll") \
  for (int mt = 0; mt < 3; ++mt) { \
    s16x8 ah = *(const s16x8*)(aTh + (mt * 16 + nl) * LDA + e0); \
    s16x8 am = *(const s16x8*)(aTm + (mt * 16 + nl) * LDA + e0); \
    _Pragma("unroll") \
    for (int nt = 0; nt < 2; ++nt) { \
      f32x4 a = acc1[mt][nt]; \
      a = __builtin_amdgcn_mfma_f32_16x16x32_bf16(ah, b1h[ks][nt], a, 0, 0, 0); \
      a = __builtin_amdgcn_mfma_f32_16x16x32_bf16(ah, b1m[ks][nt], a, 0, 0, 0); \
      a = __builtin_amdgcn_mfma_f32_16x16x32_bf16(am, b1h[ks][nt], a, 0, 0, 0); \
      acc1[mt][nt] = a; \
    } \
  } }

#define G2STEP(ks) { \
  const int c0 = (ks) * 32 + quad * 8; \
  _Pragma("unroll") \
  for (int mt = 0; mt < 3; ++mt) { \
    s16x8 ah = *(const s16x8*)(Yth + (mt * 16 + nl) * LDY + c0); \
    s16x8 am = *(const s16x8*)(Ytm + (mt * 16 + nl) * LDY + c0); \
    _Pragma("unroll") \
    for (int nt = 0; nt < 2; ++nt) { \
      f32x4 a = acc2[mt][nt]; \
      a = __builtin_amdgcn_mfma_f32_16x16x32_bf16(ah, w2h[ks][nt], a, 0, 0, 0); \
      a = __builtin_amdgcn_mfma_f32_16x16x32_bf16(ah, w2m[ks][nt], a, 0, 0, 0); \
      a = __builtin_amdgcn_mfma_f32_16x16x32_bf16(am, w2h[ks][nt], a, 0, 0, 0); \
      acc2[mt][nt] = a; \
    } \
  } }

__global__ __launch_bounds__(512, 4) void affine_vnrelu_mfma(
    const float* __restrict__ X, const float* __restrict__ J,
    const unsigned short* __restrict__ M3h, const unsigned short* __restrict__ M3m,
    const unsigned short* __restrict__ Wh, const unsigned short* __restrict__ Wm,
    float* __restrict__ out) {
  __shared__ unsigned short smem[2 * 48 * LDA + 2 * 48 * LDY];  // 76800 B
  unsigned short* aTh = smem;
  unsigned short* aTm = smem + 48 * LDA;
  unsigned short* Yth = smem + 2 * 48 * LDA;
  unsigned short* Ytm = Yth + 48 * LDY;

  const int tid = threadIdx.x;
  const int lane = tid & 63;
  const int w = tid >> 6;          // wave 0..7 -> f slice [32w, 32w+32)
  const int quad = lane >> 4;
  const int nl = lane & 15;
  const long g0 = (long)blockIdx.x * TT;
  const int b = (int)(g0 >> 12);   // N = 4096
  const int n0 = (int)(g0 & 4095);
  const int f0 = w * 32;
  const int fB1 = (f0 + nl) * 128 + quad * 8;
  const int fB2 = (f0 + nl) * 256 + quad * 8;
  const f32x4 zz = {0.f, 0.f, 0.f, 0.f};

  // ---- early issue: first half of GEMM1 B-tiles (latency under phase A) ----
  s16x8 b1h[4][2], b1m[4][2];
  B1LOAD(0); B1LOAD(1);

  // ---------------- Phase A (vectorized): 1 thread = 4 channels of 1 token --
  {
    int t = tid >> 5;                 // token 0..15
    int dch0 = (tid & 31) * 4;        // channel group
    const float* Xp = X + ((g0 + t) * 128 + dch0) * 3;   // 48B, 16B-aligned
    const float* Jp = J + ((g0 + t) * 128 + dch0) * 6;   // 96B, 16B-aligned
    float xf[12], jf[24];
    #pragma unroll
    for (int q = 0; q < 3; ++q) *(float4*)(xf + 4 * q) = ((const float4*)Xp)[q];
    #pragma unroll
    for (int q = 0; q < 6; ++q) *(float4*)(jf + 4 * q) = ((const float4*)Jp)[q];

    unsigned short hs[3][4], ms[3][4];
    #pragma unroll
    for (int e = 0; e < 4; ++e) {
      float x0 = xf[3 * e], x1 = xf[3 * e + 1], x2 = xf[3 * e + 2];
      float j0 = jf[6 * e],     j1 = jf[6 * e + 1], j2 = jf[6 * e + 2];
      float j3 = jf[6 * e + 3], j4 = jf[6 * e + 4], j5 = jf[6 * e + 5];
      float c00 = j0, c01 = j2, c02 = j4;          // col0 of the 3x2
      float a20 = j1, a21 = j3, a22 = j5;          // col1
      float n1 = sqrtf(c00 * c00 + c01 * c01 + c02 * c02);
      float inv1 = 1.0f / fmaxf(n1, 1e-12f);
      float b10 = c00 * inv1, b11 = c01 * inv1, b12 = c02 * inv1;
      float pr = b10 * a20 + b11 * a21 + b12 * a22;
      float u0 = a20 - pr * b10, u1 = a21 - pr * b11, u2 = a22 - pr * b12;
      float n2 = sqrtf(u0 * u0 + u1 * u1 + u2 * u2);
      float inv2 = 1.0f / fmaxf(n2, 1e-12f);
      float b20 = u0 * inv2, b21 = u1 * inv2, b22 = u2 * inv2;
      float b30 = b11 * b22 - b12 * b21;
      float b31 = b12 * b20 - b10 * b22;
      float b32 = b10 * b21 - b11 * b20;
      split2(b10 * x0 + b11 * x1 + b12 * x2, hs[0][e], ms[0][e]);
      split2(b20 * x0 + b21 * x1 + b22 * x2, hs[1][e], ms[1][e]);
      split2(b30 * x0 + b31 * x1 + b32 * x2, hs[2][e], ms[2][e]);
    }
    #pragma unroll
    for (int i = 0; i < 3; ++i) {
      short4 vh, vm;
      vh.x = hs[i][0]; vh.y = hs[i][1]; vh.z = hs[i][2]; vh.w = hs[i][3];
      vm.x = ms[i][0]; vm.y = ms[i][1]; vm.z = ms[i][2]; vm.w = ms[i][3];
      int ro = (i * 16 + t) * LDA + dch0;
      *(short4*)(aTh + ro) = vh;    // 8B-aligned (LDA even, dch0%4==0)
      *(short4*)(aTm + ro) = vm;
    }
  }
  __syncthreads();   // barrier 1: aT ready

  // ---------------- GEMM1: Y[j][f] = sum_e aT[j][e] * M3[f][e] --------------
  f32x4 acc1[3][2];
  #pragma unroll
  for (int mt = 0; mt < 3; ++mt)
    #pragma unroll
    for (int nt = 0; nt < 2; ++nt) acc1[mt][nt] = zz;

  B1LOAD(2); B1LOAD(3);          // in flight under steps 0-1
  G1STEP(0);
  G1STEP(1);
  G1STEP(2);
  G1STEP(3);

  // ---- issue GEMM2 W-tiles ks0-1 (drained at barrier 2, hidden by stash) ---
  s16x8 w2h[8][2], w2m[8][2];
  W2LOAD(0); W2LOAD(1);

  // ---------------- stash Y as bf16x2; acc1 dies here -----------------------
  #pragma unroll
  for (int mt = 0; mt < 3; ++mt)
    #pragma unroll
    for (int nt = 0; nt < 2; ++nt)
      #pragma unroll
      for (int r = 0; r < 4; ++r) {
        unsigned short h, m;
        split2(acc1[mt][nt][r], h, m);
        int yo = (mt * 16 + quad * 4 + r) * LDY + f0 + nt * 16 + nl;
        Yth[yo] = h; Ytm[yo] = m;
      }
  __syncthreads();   // barrier 2: Yt ready

  // ---------------- GEMM2: d[j][o] = sum_c Yt[j][c] * W[o][c] ---------------
  f32x4 acc2[3][2];
  #pragma unroll
  for (int mt = 0; mt < 3; ++mt)
    #pragma unroll
    for (int nt = 0; nt < 2; ++nt) acc2[mt][nt] = zz;

  W2LOAD(2);
  G2STEP(0);
  W2LOAD(3);
  G2STEP(1);
  W2LOAD(4);
  G2STEP(2);
  W2LOAD(5);
  G2STEP(3);
  W2LOAD(6);
  G2STEP(4);
  W2LOAD(7);
  G2STEP(5);
  G2STEP(6);
  G2STEP(7);

  // ---------------- VN-LeakyReLU + float4 stores ----------------------------
  // x re-read from Yt stash (x̂ = h+m, err ~2^-16·|x| — R6-validated, absmax
  // unchanged at 0.5). d_i = acc2[i][nt][r] at f = f0+nt*16+nl, t = quad*4+r.
  #pragma unroll
  for (int nt = 0; nt < 2; ++nt) {
    int f = f0 + nt * 16 + nl;
    float* ob = out + ((long)(b * 256 + f) * 3) * 4096 + n0 + quad * 4;
    float o[3][4];
    #pragma unroll
    for (int r = 0; r < 4; ++r) {
      int row = quad * 4 + r;
      float x0 = bf2f(Yth[row * LDY + f])        + bf2f(Ytm[row * LDY + f]);
      float x1 = bf2f(Yth[(16 + row) * LDY + f]) + bf2f(Ytm[(16 + row) * LDY + f]);
      float x2 = bf2f(Yth[(32 + row) * LDY + f]) + bf2f(Ytm[(32 + row) * LDY + f]);
      float d0 = acc2[0][nt][r], d1 = acc2[1][nt][r], d2 = acc2[2][nt][r];
      float dot = x0 * d0 + x1 * d1 + x2 * d2;
      float dn = d0 * d0 + d1 * d1 + d2 * d2;
      float s = (dot < 0.0f) ? (0.8f * dot / (dn + 1e-6f)) : 0.0f;
      o[0][r] = x0 - s * d0;
      o[1][r] = x1 - s * d1;
      o[2][r] = x2 - s * d2;
    }
    #pragma unroll
    for (int i = 0; i < 3; ++i)
      *(float4*)(ob + ((long)i * 4096)) = make_float4(o[i][0], o[i][1], o[i][2], o[i][3]);
  }
}

extern "C" void kernel_launch(void* const* d_in, const int* in_sizes, int n_in,
                              void* d_out, int out_size, void* d_ws, size_t ws_size,
                              hipStream_t stream) {
  const float* X = (const float*)d_in[0];   // [8,4096,128,3]
  const float* J = (const float*)d_in[1];   // [8,4096,128,3,2]
  const float* A = (const float*)d_in[2];   // [256,128]
  const float* B = (const float*)d_in[3];   // [256,128]
  const float* C = (const float*)d_in[4];   // [256,128]
  const float* W = (const float*)d_in[5];   // [256,256]
  unsigned short* M3h = (unsigned short*)d_ws;        // 32768 u16
  unsigned short* M3m = M3h + 128 * 256;
  unsigned short* Wh  = M3m + 128 * 256;              // 65536 u16
  unsigned short* Wm  = Wh + 256 * 256;               // total 384 KB of ws
  float* out = (float*)d_out;               // [8,256,3,4096]

  prep_kernel<<<(128 * 256 + 256 * 256) / 256, 256, 0, stream>>>(
      A, B, C, W, M3h, M3m, Wh, Wm);
  affine_vnrelu_mfma<<<NBLK, 512, 0, stream>>>(
      X, J, M3h, M3m, Wh, Wm, out);
}